// Round 9
// baseline (144.129 us; speedup 1.0000x reference)
//
#include <hip/hip_runtime.h>
#include <hip/hip_bf16.h>

// AdaptiveHighPassFilter: conv3x3(64->9, zero-pad) -> softmax(taps) -> hamming
// renorm -> CARAFE(3x3, reflect) -> 2x - lowpass.
//
// R9 theory: R2-R8 all scatter every global instruction across channel planes
// at 64KB power-of-2 stride (loads: 8 planes/inst; stores: 4 planes/inst in
// 64B half-lines, WRITE_SIZE 44MB vs 33.5 ideal). This round every global
// load/store instruction touches ONE channel plane, contiguous:
//  - tile 32x4 (128 thr, 2 waves); staging = (c-quad,y) tasks: 4 contiguous
//    64-lane dword loads (256B, 2 lines, one plane) -> packed ds_write_b64.
//  - stores: carafe output transposed via per-wave LDS obuf[64][33] then
//    written as full 128B lines, 2 channels per instruction.
//  - unchanged: MFMA conv, register carafe, shuffle mask broadcast, prep
//    A-frags in d_ws, XCD swizzle (image k -> XCD k).

typedef __attribute__((ext_vector_type(8))) short short8;
typedef __attribute__((ext_vector_type(4))) float floatx4;
typedef __attribute__((ext_vector_type(4))) unsigned uint4v;
typedef __attribute__((ext_vector_type(2))) unsigned uint2v;
typedef __attribute__((ext_vector_type(2))) float float2v;

#define IH 128
#define IW 128
#define CCH 64
#define TSX 32
#define TSY 4
#define TPX 34
#define TPY 6
#define CSH 72    // shorts per position: 144B row, 16B-aligned

__device__ __forceinline__ unsigned short f2bf(float f) {
    unsigned u = __float_as_uint(f);
    u += 0x7FFFu + ((u >> 16) & 1u);     // round-to-nearest-even
    return (unsigned short)(u >> 16);
}
__device__ __forceinline__ unsigned pkbf(float a, float b) {
    union { __hip_bfloat162 h; unsigned u; } cv;
    cv.h = __float22bfloat162_rn(float2{a, b});
    return cv.u;
}
__device__ __forceinline__ float2v unpk(unsigned u) {
    float2v r;
    r.x = __uint_as_float(u << 16);
    r.y = __uint_as_float(u & 0xFFFF0000u);
    return r;
}

// ---- prep: W[9][64][3][3] f32 -> bf16 A-fragments ws[s][lane][8shorts]
__global__ void ahpf_prep(const float* __restrict__ Wg,
                          unsigned short* __restrict__ wsp)
{
    const int i = blockIdx.x * 256 + threadIdx.x;   // 0..1151
    if (i >= 18 * 64) return;
    const int s = i >> 6, l = i & 63;
    const int fm = l & 15, fq = l >> 4;
    const int tap = s >> 1, cb = (s & 1) * 32 + fq * 8;
    short8 v = (short8)0;
    if (fm < 9) {
#pragma unroll
        for (int jj = 0; jj < 8; ++jj)
            v[jj] = (short)f2bf(Wg[fm * 576 + (cb + jj) * 9 + tap]);
    }
    ((short8*)wsp)[i] = v;
}

template <bool USE_WS>
__global__ __launch_bounds__(128, 2) void ahpf_kernel(
    const float* __restrict__ x, const float* __restrict__ Wg,
    const float* __restrict__ bias, float* __restrict__ out,
    const unsigned short* __restrict__ wsp)
{
    __shared__ __align__(16) unsigned short sx[TPY * TPX * CSH]; // 29,376 B
    __shared__ __align__(16) float obuf[2 * 64 * 33];            // 16,896 B

    const int tid  = threadIdx.x;
    const int lane = tid & 63;
    const int wv   = tid >> 6;

    // XCD swizzle: image k -> XCD k (128 tiles per image)
    const unsigned flat = blockIdx.x;
    const unsigned nid  = (flat & 7u) * 128u + (flat >> 3);
    const int bx = nid & 3, by = (nid >> 2) & 31, bz = nid >> 7;

    const int ty0 = by * TSY;
    const int tx0 = bx * TSX;
    const size_t hw = (size_t)IH * IW;
    const float* xb = x + (size_t)bz * CCH * hw;

    const int fm = lane & 15;   // conv: pixel col n within group / A row m
    const int fq = lane >> 4;

    // ---- staging: 64-float x-window, lane = x. (c-quad, y) tasks: 4
    // contiguous single-plane loads -> one ds_write_b64 (bf16 x4).
    {
        const int gx0 = (bx == 0) ? 0 : (bx == 3 ? 64 : tx0 - 16);
        const int gx  = gx0 + lane;
        const int xx  = gx - tx0 + 1;
        const bool in_tile = (xx >= 0) & (xx < TPX);
        const bool xlo = (bx == 0) & (gx == 1);     // xx=0 <- reflect(-1)=1
        const bool xhi = (bx == 3) & (gx == 126);   // xx=33 <- reflect(128)=126
#pragma unroll 2
        for (int t = wv; t < 96; t += 2) {          // 16 c-quads x 6 rows
            const int cq = t & 15, y = t >> 4;
            int gy = ty0 + y - 1;
            gy = gy < 0 ? -gy : (gy >= IH ? 2 * IH - 2 - gy : gy);
            const float* src = xb + (size_t)(4 * cq) * hw + (size_t)gy * IW + gx;
            const float v0 = src[0];
            const float v1 = src[hw];
            const float v2 = src[2 * hw];
            const float v3 = src[3 * hw];
            uint2v pk;
            pk.x = pkbf(v0, v1);
            pk.y = pkbf(v2, v3);
            const int rowb = y * TPX;
            if (in_tile) *(uint2v*)&sx[(rowb + xx) * CSH + 4 * cq] = pk;
            if (xlo)     *(uint2v*)&sx[(rowb +  0) * CSH + 4 * cq] = pk;
            if (xhi)     *(uint2v*)&sx[(rowb + 33) * CSH + 4 * cq] = pk;
        }
    }

    // ---- A-fragments: 18 coalesced b128 loads (L2/L3-hot)
    short8 afr[18];
    if (USE_WS) {
        const short8* wf = (const short8*)wsp;
#pragma unroll
        for (int s = 0; s < 18; ++s) afr[s] = wf[s * 64 + lane];
    } else {
#pragma unroll
        for (int s = 0; s < 18; ++s) {
            short8 a = (short8)0;
            if (fm < 9) {
                const int tap = s >> 1, cb = (s & 1) * 32 + fq * 8;
                const float* wp = Wg + fm * 576 + tap;
#pragma unroll
                for (int jj = 0; jj < 8; ++jj)
                    a[jj] = (short)f2bf(wp[(cb + jj) * 9]);
            }
            afr[s] = a;
        }
    }
    float bq[4];
#pragma unroll
    for (int r = 0; r < 4; ++r) {
        const int t = fq * 4 + r;
        bq[r] = (t < 9) ? bias[t] : 0.0f;
    }
    __syncthreads();

    const bool border = (bx == 0) | (bx == 3) | (by == 0) | (by == 31);
    const int n = fm;
    float* ob_w = obuf + wv * (64 * 33);

    // ---- 4 groups: (local row = 2*wv + (g>>1), col half = g&1)
#pragma unroll 1
    for (int g = 0; g < 4; ++g) {
        const int rl  = 2 * wv + (g >> 1);
        const int cb  = (g & 1) * 16;
        const int n16 = cb + n;
        const int h   = ty0 + rl, w = tx0 + n16;

        short8 bfr[18];
#pragma unroll
        for (int s = 0; s < 18; ++s) {
            const int tap = s >> 1;
            const int dy = tap / 3 - 1, dx = tap % 3 - 1;
            bfr[s] = *(const short8*)&sx[((rl + 1 + dy) * TPX + (n16 + 1 + dx)) * CSH
                                         + (s & 1) * 32 + fq * 8];
        }

        floatx4 acc = {0.f, 0.f, 0.f, 0.f};
        if (border) {
#pragma unroll
            for (int s = 0; s < 18; ++s) {
                const int tap = s >> 1;
                const int dy = tap / 3 - 1, dx = tap % 3 - 1;
                const int hy = h + dy, wx = w + dx;
                short8 bb = bfr[s];
                if (hy < 0 || hy >= IH || wx < 0 || wx >= IW) bb = (short8)0;
                acc = __builtin_amdgcn_mfma_f32_16x16x32_bf16(afr[s], bb, acc, 0, 0, 0);
            }
        } else {
#pragma unroll
            for (int s = 0; s < 18; ++s)
                acc = __builtin_amdgcn_mfma_f32_16x16x32_bf16(afr[s], bfr[s], acc, 0, 0, 0);
        }

        // softmax*hamming (denom cancels); lane holds taps fq*4+r of pixel n16
        auto hamt = [](int t) {
            const float a = (t / 3 == 1) ? 1.f : 0.08f;
            const float b = (t % 3 == 1) ? 1.f : 0.08f;
            return a * b;
        };
        const int nval = (fq < 2) ? 4 : (fq == 2 ? 1 : 0);
        float e0 = 0, e1 = 0, e2 = 0, e3 = 0, ssum = 0;
        if (nval >= 1) { e0 = __expf(acc[0] + bq[0]) * hamt(fq * 4 + 0); ssum += e0; }
        if (nval >= 4) { e1 = __expf(acc[1] + bq[1]) * hamt(fq * 4 + 1); ssum += e1;
                         e2 = __expf(acc[2] + bq[2]) * hamt(fq * 4 + 2); ssum += e2;
                         e3 = __expf(acc[3] + bq[3]) * hamt(fq * 4 + 3); ssum += e3; }
        ssum += __shfl_xor(ssum, 16);
        ssum += __shfl_xor(ssum, 32);
        const float inv = 1.0f / ssum;

        // broadcast 9 taps to every lane of pixel n (bf16-packed, 5 shuffles)
        const unsigned p01 = pkbf(e0 * inv, e1 * inv);
        const unsigned p23 = pkbf(e2 * inv, e3 * inv);
        const unsigned q0 = (unsigned)__shfl((int)p01, n);
        const unsigned q1 = (unsigned)__shfl((int)p23, n);
        const unsigned q2 = (unsigned)__shfl((int)p01, 16 + n);
        const unsigned q3 = (unsigned)__shfl((int)p23, 16 + n);
        const unsigned q4 = (unsigned)__shfl((int)p01, 32 + n);
        float mk[9];
        { float2v m;
          m = unpk(q0); mk[0] = m.x; mk[1] = m.y;
          m = unpk(q1); mk[2] = m.x; mk[3] = m.y;
          m = unpk(q2); mk[4] = m.x; mk[5] = m.y;
          m = unpk(q3); mk[6] = m.x; mk[7] = m.y;
          mk[8] = unpk(q4).x; }

        // carafe from registers: lane covers ch {8fq..}+{32+8fq..} of pixel n16
        float2v l[8];
#pragma unroll
        for (int q = 0; q < 8; ++q) l[q] = (float2v)0.f;
#pragma unroll
        for (int t = 0; t < 9; ++t) {
            const float mt = mk[t];
            const uint4v b0 = *(const uint4v*)&bfr[2 * t];
            const uint4v b1 = *(const uint4v*)&bfr[2 * t + 1];
#pragma unroll
            for (int q = 0; q < 4; ++q) {
                l[q]     += mt * unpk(b0[q]);
                l[q + 4] += mt * unpk(b1[q]);
            }
        }
        // output -> per-wave transpose buffer obuf[c][33] (stride 33: 2-way max)
        const uint4v c0 = *(const uint4v*)&bfr[8];
        const uint4v c1 = *(const uint4v*)&bfr[9];
#pragma unroll
        for (int q = 0; q < 4; ++q) {
            const float2v oe = 2.f * unpk(c0[q]) - l[q];
            const float2v oo = 2.f * unpk(c1[q]) - l[q + 4];
            ob_w[(8 * fq + 2 * q)      * 33 + n16] = oe.x;
            ob_w[(8 * fq + 2 * q + 1)  * 33 + n16] = oe.y;
            ob_w[(32 + 8 * fq + 2 * q) * 33 + n16] = oo.x;
            ob_w[(33 + 8 * fq + 2 * q) * 33 + n16] = oo.y;  // c = 32+8fq+2q+1
        }

        // after both col-halves of this row: store 32 full 128B lines,
        // 2 channels per instruction, contiguous within one channel plane.
        if (g & 1) {
            const int ci0 = lane >> 5;          // 0 or 1
            const int col = lane & 31;
            float* obase = out + (size_t)bz * CCH * hw
                         + (size_t)h * IW + tx0 + col;
#pragma unroll 8
            for (int i = 0; i < 32; ++i) {
                const int c = 2 * i + ci0;
                obase[(size_t)c * hw] = ob_w[c * 33 + col];
            }
        }
    }
}

extern "C" void kernel_launch(void* const* d_in, const int* in_sizes, int n_in,
                              void* d_out, int out_size, void* d_ws, size_t ws_size,
                              hipStream_t stream) {
    const float* x    = (const float*)d_in[0];
    const float* Wg   = (const float*)d_in[1];
    const float* bias = (const float*)d_in[2];
    float* out        = (float*)d_out;
    const int B = in_sizes[0] / (CCH * IH * IW);
    const int nblk = B * 128;   // 1024 for B=8

    if (ws_size >= 18 * 64 * 16) {
        unsigned short* wsp = (unsigned short*)d_ws;
        ahpf_prep<<<5, 256, 0, stream>>>(Wg, wsp);
        ahpf_kernel<true><<<nblk, 128, 0, stream>>>(x, Wg, bias, out, wsp);
    } else {
        ahpf_kernel<false><<<nblk, 128, 0, stream>>>(x, Wg, bias, out, nullptr);
    }
}